// Round 3
// baseline (129.430 us; speedup 1.0000x reference)
//
#include <hip/hip_runtime.h>
#include <hip/hip_bf16.h>
#include <math.h>

// Problem constants
#define BATCH 8
#define HH 512
#define WW 512
#define COUT 256
#define NPTS 11          // 5 + 6
#define CASC 3
#define FH 128           // conv output spatial
#define FW 128
#define KT 49            // 7x7 taps
#define NBK (BATCH*NPTS) // 88
#define NSPLIT 8         // argmax row-splits per (b,k) map
#define OROWS (HH/NSPLIT) // 64 output rows per split
#define NABLK (NBK*NSPLIT) // 704 argmax blocks

// ws layout (floats)
#define FOLD_OFF   0          // 850 floats: scoreW[11][49], scoreB[11], shiftW[6][49], shiftB[6]
#define SCORES_OFF 1024       // 8*11*128*128 = 1441792 floats
#define PVAL_OFF   (1024 + 1441792)         // 704 floats
#define PIDX_OFF   (PVAL_OFF + 704)         // 704 ints
#define CNT_OFF    (PIDX_OFF + 704)         // 1 int (completion counter)

#define STEPC (127.0f/511.0f)

// ---------------------------------------------------------------------------
// Kernel 1: fold weights. Also zeroes the argmax completion counter (ws is
// re-poisoned to 0xAA before every call; kernel-boundary ordering guarantees
// the zero lands before argmax_cascade starts).
__global__ __launch_bounds__(64) void fold_kernel(
    const float* __restrict__ bw, const float* __restrict__ bb,
    const float* __restrict__ fcw, const float* __restrict__ fcb,
    const float* __restrict__ hw, const float* __restrict__ hb,
    float* __restrict__ fold, int* __restrict__ cnt) {
  int id = blockIdx.x;          // 0..849
  if (id == 0 && threadIdx.x == 0) cnt[0] = 0;
  int row = id / 50, t = id % 50;
  int lane = threadIdx.x;       // 0..63
  float acc = 0.f;
  for (int c = lane; c < COUT; c += 64) {
    float coef;
    if (row < NPTS) {
      coef = fcw[row*COUT + c];
    } else {
      int r = row - NPTS;
      coef = hw[(r >> 1)*(COUT*2) + c*2 + (r & 1)];
    }
    float wsum;
    if (t < KT) {
      const float* p = bw + c*(3*KT) + t;
      wsum = p[0] + p[KT] + p[2*KT];
    } else {
      wsum = bb[c];
    }
    acc += coef * wsum;
  }
  #pragma unroll
  for (int off = 32; off > 0; off >>= 1) acc += __shfl_down(acc, off);
  if (lane == 0) {
    if (t == KT) acc += (row < NPTS) ? fcb[row] : hb[row - NPTS];
    if (row < NPTS) {
      if (t < KT) fold[row*KT + t] = acc;
      else        fold[NPTS*KT + row] = acc;                  // scoreB at 539..549
    } else {
      int r = row - NPTS;
      if (t < KT) fold[550 + r*KT + t] = acc;                 // shiftW
      else        fold[844 + r] = acc;                        // shiftB
    }
  }
}

// ---------------------------------------------------------------------------
// Kernel 2: scores (8,11,128,128) via folded 7x7 stride-4 conv on (img-0.5).
// Weights read from global with loop-uniform indices -> scalar-cache s_loads.
__global__ __launch_bounds__(256) void scores_kernel(
    const float* __restrict__ img, const float* __restrict__ fold,
    float* __restrict__ scores) {
  int g = blockIdx.x*256 + threadIdx.x;     // 0..131071
  int b = g >> 14;
  int rem = g & 16383;
  int y = rem >> 7, x = rem & 127;
  const float* im = img + (size_t)b * (HH*WW);
  float acc[NPTS];
  #pragma unroll
  for (int k = 0; k < NPTS; ++k) acc[k] = fold[NPTS*KT + k];   // uniform -> s_load
  int iy0 = y*4 - 3, ix0 = x*4 - 3;
  #pragma unroll
  for (int kh = 0; kh < 7; ++kh) {
    int iy = iy0 + kh;
    if (iy < 0 || iy >= HH) continue;
    #pragma unroll
    for (int kw = 0; kw < 7; ++kw) {
      int ix = ix0 + kw;
      if (ix < 0 || ix >= WW) continue;
      float xv = im[iy*WW + ix] - 0.5f;
      int t = kh*7 + kw;
      #pragma unroll
      for (int k = 0; k < NPTS; ++k) acc[k] = fmaf(fold[k*KT + t], xv, acc[k]);
    }
  }
  float* out = scores + (size_t)b * (NPTS*FH*FW) + rem;
  #pragma unroll
  for (int k = 0; k < NPTS; ++k) out[(size_t)k*(FH*FW)] = acc[k];
}

// ---------------------------------------------------------------------------
// Kernel 3: argmax over the 512x512 bilinear(align_corners) upsample of each
// (b,k) score map, fused with the cascade via the deadlock-free last-block
// pattern. Per-point arithmetic bit-identical to R1/R2 (absmax 0.0).
// Block reduction: intra-wave shuffles (no barriers) + 4-leader LDS hop.
__global__ __launch_bounds__(256) void argmax_cascade_kernel(
    const float* __restrict__ scores, const float* __restrict__ img,
    const float* __restrict__ fold,
    float* __restrict__ pval, int* __restrict__ pidx,
    int* __restrict__ cnt, float* __restrict__ out) {
  __shared__ float s[20*128];
  __shared__ float wv[4];
  __shared__ int   wi[4];
  __shared__ int   isLast;
  int bk = blockIdx.x / NSPLIT;
  int q  = blockIdx.x % NSPLIT;
  const float* src = scores + (size_t)bk * (FH*FW);

  int oyb = q*OROWS;
  int ybase = (int)((float)oyb * STEPC);
  int ylast = (int)((float)(oyb + OROWS - 1) * STEPC);
  int yend  = min(ylast + 1, FH - 1);
  int rows  = yend - ybase + 1;              // <= 18
  for (int i = threadIdx.x; i < rows*FW; i += 256) s[i] = src[ybase*FW + i];
  __syncthreads();

  // per-thread x columns (constant over oy)
  int ox0 = threadIdx.x*2, ox1 = ox0 + 1;
  float tx0 = (float)ox0 * STEPC, tx1 = (float)ox1 * STEPC;
  int xa0 = (int)tx0, xb0 = (int)tx1;
  float wx0 = tx0 - (float)xa0, wx1 = tx1 - (float)xb0;
  int xa1 = min(xa0 + 1, FW - 1), xb1 = min(xb0 + 1, FW - 1);
  float omwx0 = 1.f - wx0, omwx1 = 1.f - wx1;

  float best = -3.4028235e38f;
  int bidx = 0x7fffffff;
  int prevY0 = -1;
  float a0=0.f, b0=0.f, c0=0.f, d0=0.f;   // point 0 corners
  float a1=0.f, b1=0.f, c1=0.f, d1=0.f;   // point 1 corners
  for (int j = 0; j < OROWS; ++j) {
    int oy = oyb + j;
    float ty = (float)oy * STEPC;
    int y0 = (int)ty;
    float wy = ty - (float)y0;
    float omwy = 1.f - wy;
    if (y0 != prevY0) {                    // wave-uniform branch
      int y1 = min(y0 + 1, FH - 1);
      const float* r0 = s + (y0 - ybase)*FW;
      const float* r1 = s + (y1 - ybase)*FW;
      a0 = r0[xa0]; b0 = r1[xa0]; c0 = r0[xa1]; d0 = r1[xa1];
      a1 = r0[xb0]; b1 = r1[xb0]; c1 = r0[xb1]; d1 = r1[xb1];
      prevY0 = y0;
    }
    {
      float top0 = a0*omwy + b0*wy;
      float top1 = c0*omwy + d0*wy;
      float v = top0*omwx0 + top1*wx0;
      if (v > best) { best = v; bidx = oy*512 + ox0; }
    }
    {
      float top0 = a1*omwy + b1*wy;
      float top1 = c1*omwy + d1*wy;
      float v = top0*omwx1 + top1*wx1;
      if (v > best) { best = v; bidx = oy*512 + ox1; }
    }
  }

  // intra-wave reduce (value desc, index asc tie-break) — no barriers
  #pragma unroll
  for (int off = 32; off > 0; off >>= 1) {
    float ov = __shfl_down(best, off);
    int   oi = __shfl_down(bidx, off);
    if (ov > best || (ov == best && oi < bidx)) { best = ov; bidx = oi; }
  }
  int wave = threadIdx.x >> 6;
  if ((threadIdx.x & 63) == 0) { wv[wave] = best; wi[wave] = bidx; }
  __syncthreads();

  if (threadIdx.x == 0) {
    best = wv[0]; bidx = wi[0];
    #pragma unroll
    for (int w = 1; w < 4; ++w) {
      float ov = wv[w]; int oi = wi[w];
      if (ov > best || (ov == best && oi < bidx)) { best = ov; bidx = oi; }
    }
    pval[bk*NSPLIT + q] = best;
    pidx[bk*NSPLIT + q] = bidx;
    __threadfence();                       // release partials
    int old = atomicAdd(cnt, 1);
    isLast = (old == NABLK - 1) ? 1 : 0;
  }
  __syncthreads();
  if (!isLast) return;

  // ---- last block only: merge partials -> coords, 3 cascade refinements ----
  __threadfence();                         // acquire other blocks' partials
  int p = threadIdx.x;                     // bk index = b*11 + k
  if (p >= NBK) return;
  float mbest = pval[p*NSPLIT]; int mbidx = pidx[p*NSPLIT];
  #pragma unroll
  for (int qq = 1; qq < NSPLIT; ++qq) {
    float v = pval[p*NSPLIT + qq]; int i = pidx[p*NSPLIT + qq];
    if (v > mbest || (v == mbest && i < mbidx)) { mbest = v; mbidx = i; }
  }
  float cx = (float)(mbidx & 511);
  float cy = (float)(mbidx >> 9);
  int b = p / NPTS;
  const float* im = img + (size_t)b * (HH*WW);
  for (int i = 0; i < CASC; ++i) {
    // hi from y-coord, wi from x-coord; jnp.round = RNE = rintf
    float ry = rintf(cy * 0.25f), rx = rintf(cx * 0.25f);
    int hi = (int)fminf(fmaxf(ry, 0.f), (float)(FH - 1));
    int wdi = (int)fminf(fmaxf(rx, 0.f), (float)(FW - 1));
    float s0 = fold[844 + i*2 + 0];
    float s1 = fold[844 + i*2 + 1];
    int iy0 = hi*4 - 3, ix0 = wdi*4 - 3;
    for (int kh = 0; kh < 7; ++kh) {
      int iy = iy0 + kh;
      if (iy < 0 || iy >= HH) continue;
      for (int kw = 0; kw < 7; ++kw) {
        int ix = ix0 + kw;
        if (ix < 0 || ix >= WW) continue;
        float xv = im[iy*WW + ix] - 0.5f;
        int t = kh*7 + kw;
        s0 = fmaf(fold[550 + (i*2 + 0)*KT + t], xv, s0);
        s1 = fmaf(fold[550 + (i*2 + 1)*KT + t], xv, s1);
      }
    }
    cx += s0;
    cy += s1;
  }
  out[p*2 + 0] = cx;
  out[p*2 + 1] = cy;
}

// ---------------------------------------------------------------------------
extern "C" void kernel_launch(void* const* d_in, const int* in_sizes, int n_in,
                              void* d_out, int out_size, void* d_ws, size_t ws_size,
                              hipStream_t stream) {
  const float* img = (const float*)d_in[0];   // (8,1,512,512)
  const float* bw  = (const float*)d_in[1];   // (256,3,7,7)
  const float* bb  = (const float*)d_in[2];   // (256,)
  const float* fcw = (const float*)d_in[3];   // (11,256)
  const float* fcb = (const float*)d_in[4];   // (11,)
  const float* hw  = (const float*)d_in[5];   // (3,256,2)
  const float* hb  = (const float*)d_in[6];   // (3,2)
  float* out = (float*)d_out;                 // (8,11,2) f32

  float* ws     = (float*)d_ws;
  float* fold   = ws + FOLD_OFF;
  float* scores = ws + SCORES_OFF;
  float* pval   = ws + PVAL_OFF;
  int*   pidx   = (int*)(ws + PIDX_OFF);
  int*   cnt    = (int*)(ws + CNT_OFF);

  fold_kernel<<<850, 64, 0, stream>>>(bw, bb, fcw, fcb, hw, hb, fold, cnt);
  scores_kernel<<<512, 256, 0, stream>>>(img, fold, scores);
  argmax_cascade_kernel<<<NABLK, 256, 0, stream>>>(scores, img, fold,
                                                   pval, pidx, cnt, out);
}

// Round 4
// 121.809 us; speedup vs baseline: 1.0626x; 1.0626x over previous
//
#include <hip/hip_runtime.h>
#include <hip/hip_bf16.h>
#include <math.h>

// Problem constants
#define BATCH 8
#define HH 512
#define WW 512
#define COUT 256
#define NPTS 11          // 5 + 6
#define CASC 3
#define FH 128           // conv output spatial
#define FW 128
#define KT 49            // 7x7 taps
#define NBK (BATCH*NPTS) // 88
#define NSPLIT 8         // argmax row-splits per (b,k) map
#define OROWS (HH/NSPLIT) // 64 output rows per split

// ws layout (floats)
#define FOLD_OFF   0          // 850 floats: scoreW[11][49], scoreB[11], shiftW[6][49], shiftB[6]
#define SCORES_OFF 1024       // 8*11*128*128 = 1441792 floats
#define PVAL_OFF   (1024 + 1441792)         // 704 floats
#define PIDX_OFF   (PVAL_OFF + 704)         // 704 ints

#define STEPC (127.0f/511.0f)

// ---------------------------------------------------------------------------
// Kernel 1: fold weights. One wave per output (850 outputs = 17 rows x 50
// cols; col 49 = bias). R4: 213 blocks x 256 threads (4 waves/block) instead
// of 850 x 64 — same work, fewer dispatch packets.
// NOTE (R3 post-mortem): do NOT fuse the downstream cascade via last-block
// atomics — 704 device-scope atomicAdd + __threadfence cost ~45 us on
// multi-XCD gfx950 (L2 writeback per release fence, serialized cross-XCD
// atomics). Separate kernels are faster.
__global__ __launch_bounds__(256) void fold_kernel(
    const float* __restrict__ bw, const float* __restrict__ bb,
    const float* __restrict__ fcw, const float* __restrict__ fcb,
    const float* __restrict__ hw, const float* __restrict__ hb,
    float* __restrict__ fold) {
  int id = blockIdx.x*4 + (threadIdx.x >> 6);   // 0..851
  if (id >= 850) return;
  int row = id / 50, t = id % 50;
  int lane = threadIdx.x & 63;
  float acc = 0.f;
  for (int c = lane; c < COUT; c += 64) {
    float coef;
    if (row < NPTS) {
      coef = fcw[row*COUT + c];
    } else {
      int r = row - NPTS;
      coef = hw[(r >> 1)*(COUT*2) + c*2 + (r & 1)];
    }
    float wsum;
    if (t < KT) {
      const float* p = bw + c*(3*KT) + t;
      wsum = p[0] + p[KT] + p[2*KT];
    } else {
      wsum = bb[c];
    }
    acc += coef * wsum;
  }
  #pragma unroll
  for (int off = 32; off > 0; off >>= 1) acc += __shfl_down(acc, off);
  if (lane == 0) {
    if (t == KT) acc += (row < NPTS) ? fcb[row] : hb[row - NPTS];
    if (row < NPTS) {
      if (t < KT) fold[row*KT + t] = acc;
      else        fold[NPTS*KT + row] = acc;                  // scoreB at 539..549
    } else {
      int r = row - NPTS;
      if (t < KT) fold[550 + r*KT + t] = acc;                 // shiftW
      else        fold[844 + r] = acc;                        // shiftB
    }
  }
}

// ---------------------------------------------------------------------------
// Kernel 2: scores (8,11,128,128) via folded 7x7 stride-4 conv on (img-0.5).
// Weights read from global with loop-uniform indices -> scalar-cache s_loads.
__global__ __launch_bounds__(256) void scores_kernel(
    const float* __restrict__ img, const float* __restrict__ fold,
    float* __restrict__ scores) {
  int g = blockIdx.x*256 + threadIdx.x;     // 0..131071
  int b = g >> 14;
  int rem = g & 16383;
  int y = rem >> 7, x = rem & 127;
  const float* im = img + (size_t)b * (HH*WW);
  float acc[NPTS];
  #pragma unroll
  for (int k = 0; k < NPTS; ++k) acc[k] = fold[NPTS*KT + k];   // uniform -> s_load
  int iy0 = y*4 - 3, ix0 = x*4 - 3;
  #pragma unroll
  for (int kh = 0; kh < 7; ++kh) {
    int iy = iy0 + kh;
    if (iy < 0 || iy >= HH) continue;
    #pragma unroll
    for (int kw = 0; kw < 7; ++kw) {
      int ix = ix0 + kw;
      if (ix < 0 || ix >= WW) continue;
      float xv = im[iy*WW + ix] - 0.5f;
      int t = kh*7 + kw;
      #pragma unroll
      for (int k = 0; k < NPTS; ++k) acc[k] = fmaf(fold[k*KT + t], xv, acc[k]);
    }
  }
  float* out = scores + (size_t)b * (NPTS*FH*FW) + rem;
  #pragma unroll
  for (int k = 0; k < NPTS; ++k) out[(size_t)k*(FH*FW)] = acc[k];
}

// ---------------------------------------------------------------------------
// Kernel 3: argmax over 512x512 bilinear(align_corners) upsample of each
// (b,k) score map. Grid = 88*NSPLIT blocks; block q handles oy in
// [q*OROWS, q*OROWS+OROWS). Corners cached in registers, reloaded from LDS
// only when y0 changes (wave-uniform, ~every 4th iter). Intra-wave shuffle
// reduction + 4-leader LDS hop. Per-point arithmetic bit-identical to
// R1/R2 (absmax 0.0). R4: float4 LDS staging.
__global__ __launch_bounds__(256) void argmax_kernel(
    const float* __restrict__ scores, float* __restrict__ pval,
    int* __restrict__ pidx) {
  __shared__ __align__(16) float s[20*128];
  __shared__ float wv[4];
  __shared__ int   wi[4];
  int bk = blockIdx.x / NSPLIT;
  int q  = blockIdx.x % NSPLIT;
  const float* src = scores + (size_t)bk * (FH*FW);

  int oyb = q*OROWS;
  int ybase = (int)((float)oyb * STEPC);
  int ylast = (int)((float)(oyb + OROWS - 1) * STEPC);
  int yend  = min(ylast + 1, FH - 1);
  int rows  = yend - ybase + 1;              // <= 18
  {
    const float4* src4 = (const float4*)(src + ybase*FW);
    float4* s4 = (float4*)s;
    int n4 = (rows*FW) >> 2;                 // rows*FW multiple of 128
    for (int i = threadIdx.x; i < n4; i += 256) s4[i] = src4[i];
  }
  __syncthreads();

  // per-thread x columns (constant over oy)
  int ox0 = threadIdx.x*2, ox1 = ox0 + 1;
  float tx0 = (float)ox0 * STEPC, tx1 = (float)ox1 * STEPC;
  int xa0 = (int)tx0, xb0 = (int)tx1;
  float wx0 = tx0 - (float)xa0, wx1 = tx1 - (float)xb0;
  int xa1 = min(xa0 + 1, FW - 1), xb1 = min(xb0 + 1, FW - 1);
  float omwx0 = 1.f - wx0, omwx1 = 1.f - wx1;

  float best = -3.4028235e38f;
  int bidx = 0x7fffffff;
  int prevY0 = -1;
  float a0=0.f, b0=0.f, c0=0.f, d0=0.f;   // point 0 corners
  float a1=0.f, b1=0.f, c1=0.f, d1=0.f;   // point 1 corners
  for (int j = 0; j < OROWS; ++j) {
    int oy = oyb + j;
    float ty = (float)oy * STEPC;
    int y0 = (int)ty;
    float wy = ty - (float)y0;
    float omwy = 1.f - wy;
    if (y0 != prevY0) {                    // wave-uniform branch
      int y1 = min(y0 + 1, FH - 1);
      const float* r0 = s + (y0 - ybase)*FW;
      const float* r1 = s + (y1 - ybase)*FW;
      a0 = r0[xa0]; b0 = r1[xa0]; c0 = r0[xa1]; d0 = r1[xa1];
      a1 = r0[xb0]; b1 = r1[xb0]; c1 = r0[xb1]; d1 = r1[xb1];
      prevY0 = y0;
    }
    {
      float top0 = a0*omwy + b0*wy;
      float top1 = c0*omwy + d0*wy;
      float v = top0*omwx0 + top1*wx0;
      if (v > best) { best = v; bidx = oy*512 + ox0; }
    }
    {
      float top0 = a1*omwy + b1*wy;
      float top1 = c1*omwy + d1*wy;
      float v = top0*omwx1 + top1*wx1;
      if (v > best) { best = v; bidx = oy*512 + ox1; }
    }
  }

  // intra-wave reduce (value desc, index asc tie-break) — no barriers
  #pragma unroll
  for (int off = 32; off > 0; off >>= 1) {
    float ov = __shfl_down(best, off);
    int   oi = __shfl_down(bidx, off);
    if (ov > best || (ov == best && oi < bidx)) { best = ov; bidx = oi; }
  }
  int wave = threadIdx.x >> 6;
  if ((threadIdx.x & 63) == 0) { wv[wave] = best; wi[wave] = bidx; }
  __syncthreads();
  if (threadIdx.x == 0) {
    best = wv[0]; bidx = wi[0];
    #pragma unroll
    for (int w = 1; w < 4; ++w) {
      float ov = wv[w]; int oi = wi[w];
      if (ov > best || (ov == best && oi < bidx)) { best = ov; bidx = oi; }
    }
    pval[bk*NSPLIT + q] = best;
    pidx[bk*NSPLIT + q] = bidx;
  }
}

// ---------------------------------------------------------------------------
// Kernel 4: merge partials -> coords, then 3 cascade refinements with folded
// shift weights (direct conv at the gathered point), write final coords.
__global__ __launch_bounds__(128) void cascade_kernel(
    const float* __restrict__ img, const float* __restrict__ fold,
    const float* __restrict__ pval, const int* __restrict__ pidx,
    float* __restrict__ out) {
  int p = threadIdx.x;    // bk index = b*11 + k
  if (p >= NBK) return;
  float best = pval[p*NSPLIT]; int bidx = pidx[p*NSPLIT];
  #pragma unroll
  for (int q = 1; q < NSPLIT; ++q) {
    float v = pval[p*NSPLIT + q]; int i = pidx[p*NSPLIT + q];
    if (v > best || (v == best && i < bidx)) { best = v; bidx = i; }
  }
  float cx = (float)(bidx & 511);
  float cy = (float)(bidx >> 9);
  int b = p / NPTS;
  const float* im = img + (size_t)b * (HH*WW);
  for (int i = 0; i < CASC; ++i) {
    // hi from y-coord, wi from x-coord; jnp.round = RNE = rintf
    float ry = rintf(cy * 0.25f), rx = rintf(cx * 0.25f);
    int hi = (int)fminf(fmaxf(ry, 0.f), (float)(FH - 1));
    int wi = (int)fminf(fmaxf(rx, 0.f), (float)(FW - 1));
    float s0 = fold[844 + i*2 + 0];
    float s1 = fold[844 + i*2 + 1];
    int iy0 = hi*4 - 3, ix0 = wi*4 - 3;
    for (int kh = 0; kh < 7; ++kh) {
      int iy = iy0 + kh;
      if (iy < 0 || iy >= HH) continue;
      for (int kw = 0; kw < 7; ++kw) {
        int ix = ix0 + kw;
        if (ix < 0 || ix >= WW) continue;
        float xv = im[iy*WW + ix] - 0.5f;
        int t = kh*7 + kw;
        s0 = fmaf(fold[550 + (i*2 + 0)*KT + t], xv, s0);
        s1 = fmaf(fold[550 + (i*2 + 1)*KT + t], xv, s1);
      }
    }
    cx += s0;
    cy += s1;
  }
  out[p*2 + 0] = cx;
  out[p*2 + 1] = cy;
}

// ---------------------------------------------------------------------------
extern "C" void kernel_launch(void* const* d_in, const int* in_sizes, int n_in,
                              void* d_out, int out_size, void* d_ws, size_t ws_size,
                              hipStream_t stream) {
  const float* img = (const float*)d_in[0];   // (8,1,512,512)
  const float* bw  = (const float*)d_in[1];   // (256,3,7,7)
  const float* bb  = (const float*)d_in[2];   // (256,)
  const float* fcw = (const float*)d_in[3];   // (11,256)
  const float* fcb = (const float*)d_in[4];   // (11,)
  const float* hw  = (const float*)d_in[5];   // (3,256,2)
  const float* hb  = (const float*)d_in[6];   // (3,2)
  float* out = (float*)d_out;                 // (8,11,2) f32

  float* ws     = (float*)d_ws;
  float* fold   = ws + FOLD_OFF;
  float* scores = ws + SCORES_OFF;
  float* pval   = ws + PVAL_OFF;
  int*   pidx   = (int*)(ws + PIDX_OFF);

  fold_kernel<<<213, 256, 0, stream>>>(bw, bb, fcw, fcb, hw, hb, fold);
  scores_kernel<<<512, 256, 0, stream>>>(img, fold, scores);
  argmax_kernel<<<NBK*NSPLIT, 256, 0, stream>>>(scores, pval, pidx);
  cascade_kernel<<<1, 128, 0, stream>>>(img, fold, pval, pidx, out);
}

// Round 5
// 119.188 us; speedup vs baseline: 1.0859x; 1.0220x over previous
//
#include <hip/hip_runtime.h>
#include <hip/hip_bf16.h>
#include <math.h>

// Problem constants
#define BATCH 8
#define HH 512
#define WW 512
#define COUT 256
#define NPTS 11          // 5 + 6
#define CASC 3
#define FH 128           // conv output spatial
#define FW 128
#define KT 49            // 7x7 taps
#define NBK (BATCH*NPTS) // 88
#define NSPLIT 8         // argmax row-splits per (b,k) map
#define OROWS (HH/NSPLIT) // 64 output rows per split

// ws layout (floats)
// fold: [0..538]   scoreW in [t][k] layout (t*11+k)
//       [539..549] scoreB[k]
//       [550..843] shiftW[i*2+j][t] (49 each)
//       [844..849] shiftB
#define FOLD_OFF   0
#define SCORES_OFF 1024       // 8*11*128*128 = 1441792 floats
#define PVAL_OFF   (1024 + 1441792)         // 704 floats
#define PIDX_OFF   (PVAL_OFF + 704)         // 704 ints

#define STEPC (127.0f/511.0f)

// ---------------------------------------------------------------------------
// Kernel 1: fold weights. One wave per output (850 outputs = 17 rows x 50
// cols; col 49 = bias). 213 blocks x 256 threads (4 waves/block).
// NOTE (R3 post-mortem): do NOT fuse the downstream cascade via last-block
// atomics — 704 device-scope atomicAdd + __threadfence cost ~45 us on
// multi-XCD gfx950. Separate kernels are faster.
__global__ __launch_bounds__(256) void fold_kernel(
    const float* __restrict__ bw, const float* __restrict__ bb,
    const float* __restrict__ fcw, const float* __restrict__ fcb,
    const float* __restrict__ hw, const float* __restrict__ hb,
    float* __restrict__ fold) {
  int id = blockIdx.x*4 + (threadIdx.x >> 6);   // 0..851
  if (id >= 850) return;
  int row = id / 50, t = id % 50;
  int lane = threadIdx.x & 63;
  float acc = 0.f;
  for (int c = lane; c < COUT; c += 64) {
    float coef;
    if (row < NPTS) {
      coef = fcw[row*COUT + c];
    } else {
      int r = row - NPTS;
      coef = hw[(r >> 1)*(COUT*2) + c*2 + (r & 1)];
    }
    float wsum;
    if (t < KT) {
      const float* p = bw + c*(3*KT) + t;
      wsum = p[0] + p[KT] + p[2*KT];
    } else {
      wsum = bb[c];
    }
    acc += coef * wsum;
  }
  #pragma unroll
  for (int off = 32; off > 0; off >>= 1) acc += __shfl_down(acc, off);
  if (lane == 0) {
    if (t == KT) acc += (row < NPTS) ? fcb[row] : hb[row - NPTS];
    if (row < NPTS) {
      if (t < KT) fold[t*NPTS + row] = acc;                   // [t][k] layout
      else        fold[NPTS*KT + row] = acc;                  // scoreB at 539..549
    } else {
      int r = row - NPTS;
      if (t < KT) fold[550 + r*KT + t] = acc;                 // shiftW
      else        fold[844 + r] = acc;                        // shiftB
    }
  }
}

// ---------------------------------------------------------------------------
// Kernel 2: scores (8,11,128,128) via folded 7x7 stride-4 conv on (img-0.5).
// Weights read from global with loop-uniform indices -> scalar-cache s_loads;
// [t][k] layout makes the 11 per-tap weights contiguous (s_load batching).
__global__ __launch_bounds__(256) void scores_kernel(
    const float* __restrict__ img, const float* __restrict__ fold,
    float* __restrict__ scores) {
  int g = blockIdx.x*256 + threadIdx.x;     // 0..131071
  int b = g >> 14;
  int rem = g & 16383;
  int y = rem >> 7, x = rem & 127;
  const float* im = img + (size_t)b * (HH*WW);
  float acc[NPTS];
  #pragma unroll
  for (int k = 0; k < NPTS; ++k) acc[k] = fold[NPTS*KT + k];   // uniform -> s_load
  int iy0 = y*4 - 3, ix0 = x*4 - 3;
  #pragma unroll
  for (int kh = 0; kh < 7; ++kh) {
    int iy = iy0 + kh;
    if (iy < 0 || iy >= HH) continue;
    #pragma unroll
    for (int kw = 0; kw < 7; ++kw) {
      int ix = ix0 + kw;
      if (ix < 0 || ix >= WW) continue;
      float xv = im[iy*WW + ix] - 0.5f;
      int t = kh*7 + kw;
      #pragma unroll
      for (int k = 0; k < NPTS; ++k) acc[k] = fmaf(fold[t*NPTS + k], xv, acc[k]);
    }
  }
  float* out = scores + (size_t)b * (NPTS*FH*FW) + rem;
  #pragma unroll
  for (int k = 0; k < NPTS; ++k) out[(size_t)k*(FH*FW)] = acc[k];
}

// ---------------------------------------------------------------------------
// Kernel 3: argmax over the 512x512 bilinear(align_corners) upsample of each
// (b,k) score map — candidate-point scan. Bilinear is linear in wx (fixed wy)
// and wy (fixed wx), so the lattice max of each score cell is at its extreme
// sampled rows/cols: candidates = {first,last row of each y-bucket} x
// {first,last col of each x-bucket} (~255x255 of 512x512, 4x fewer evals).
// Integer candidate formula ceil(k*511/127) provably matches the fp bucket
// map (non-integer i*127/511 is >=1/511 from integers >> fp error).
// Per-point arithmetic verbatim from R1 (absmax 0.0 for 4 rounds).
__global__ __launch_bounds__(256) void argmax_kernel(
    const float* __restrict__ scores, float* __restrict__ pval,
    int* __restrict__ pidx) {
  __shared__ __align__(16) float s[20*128];
  __shared__ float wvv[4];
  __shared__ int   wvi[4];
  int bk = blockIdx.x / NSPLIT;
  int q  = blockIdx.x % NSPLIT;
  const float* src = scores + (size_t)bk * (FH*FW);

  int oyb = q*OROWS;
  int ybase = (int)((float)oyb * STEPC);
  int ylast = (int)((float)(oyb + OROWS - 1) * STEPC);
  int yend  = min(ylast + 1, FH - 1);
  int rows  = yend - ybase + 1;              // <= 18
  {
    const float4* src4 = (const float4*)(src + ybase*FW);
    float4* s4 = (float4*)s;
    int n4 = (rows*FW) >> 2;                 // rows*FW multiple of 128
    for (int i = threadIdx.x; i < n4; i += 256) s4[i] = src4[i];
  }
  __syncthreads();

  // per-thread candidate column: thread t owns x-bucket t>>1, (t&1 ? last :
  // first) sampled col of that bucket. kb=127 is the singleton {511} (dup ok).
  int t = threadIdx.x;
  int kb = t >> 1;
  int cf = (kb*511 + 126)/127;
  int cl = (kb < 127) ? ((kb + 1)*511 + 126)/127 - 1 : 511;
  int ox = (t & 1) ? cl : cf;
  float tx = (float)ox * STEPC;
  int xa0 = (int)tx;
  float wx = tx - (float)xa0;
  int xa1 = min(xa0 + 1, FW - 1);
  float omwx = 1.f - wx;

  float best = -3.4028235e38f;
  int bidx = 0x7fffffff;
  for (int k = ybase; k <= ylast; ++k) {     // y-buckets intersecting split
    int y1 = min(k + 1, FH - 1);
    const float* r0 = s + (k  - ybase)*FW;
    const float* r1 = s + (y1 - ybase)*FW;
    float A = r0[xa0], B = r1[xa0], C = r0[xa1], D = r1[xa1];
    int rf = (k*511 + 126)/127;                              // first row of bucket
    int rl = (k < 127) ? ((k + 1)*511 + 126)/127 - 1 : 511;  // last row
    if (rf >= oyb && rf < oyb + OROWS) {
      float ty = (float)rf * STEPC;
      int y0i = (int)ty;
      float wy = ty - (float)y0i;
      float omwy = 1.f - wy;
      float top0 = A*omwy + B*wy;
      float top1 = C*omwy + D*wy;
      float v = top0*omwx + top1*wx;
      if (v > best) { best = v; bidx = rf*512 + ox; }
    }
    if (rl != rf && rl >= oyb && rl < oyb + OROWS) {
      float ty = (float)rl * STEPC;
      int y0i = (int)ty;
      float wy = ty - (float)y0i;
      float omwy = 1.f - wy;
      float top0 = A*omwy + B*wy;
      float top1 = C*omwy + D*wy;
      float v = top0*omwx + top1*wx;
      if (v > best) { best = v; bidx = rl*512 + ox; }
    }
  }

  // intra-wave reduce (value desc, index asc tie-break) — no barriers
  #pragma unroll
  for (int off = 32; off > 0; off >>= 1) {
    float ov = __shfl_down(best, off);
    int   oi = __shfl_down(bidx, off);
    if (ov > best || (ov == best && oi < bidx)) { best = ov; bidx = oi; }
  }
  int wave = threadIdx.x >> 6;
  if ((threadIdx.x & 63) == 0) { wvv[wave] = best; wvi[wave] = bidx; }
  __syncthreads();
  if (threadIdx.x == 0) {
    best = wvv[0]; bidx = wvi[0];
    #pragma unroll
    for (int w = 1; w < 4; ++w) {
      float ov = wvv[w]; int oi = wvi[w];
      if (ov > best || (ov == best && oi < bidx)) { best = ov; bidx = oi; }
    }
    pval[bk*NSPLIT + q] = best;
    pidx[bk*NSPLIT + q] = bidx;
  }
}

// ---------------------------------------------------------------------------
// Kernel 4: merge partials -> coords, then 3 cascade refinements with folded
// shift weights (direct conv at the gathered point), write final coords.
__global__ __launch_bounds__(128) void cascade_kernel(
    const float* __restrict__ img, const float* __restrict__ fold,
    const float* __restrict__ pval, const int* __restrict__ pidx,
    float* __restrict__ out) {
  int p = threadIdx.x;    // bk index = b*11 + k
  if (p >= NBK) return;
  float best = pval[p*NSPLIT]; int bidx = pidx[p*NSPLIT];
  #pragma unroll
  for (int q = 1; q < NSPLIT; ++q) {
    float v = pval[p*NSPLIT + q]; int i = pidx[p*NSPLIT + q];
    if (v > best || (v == best && i < bidx)) { best = v; bidx = i; }
  }
  float cx = (float)(bidx & 511);
  float cy = (float)(bidx >> 9);
  int b = p / NPTS;
  const float* im = img + (size_t)b * (HH*WW);
  for (int i = 0; i < CASC; ++i) {
    // hi from y-coord, wi from x-coord; jnp.round = RNE = rintf
    float ry = rintf(cy * 0.25f), rx = rintf(cx * 0.25f);
    int hi = (int)fminf(fmaxf(ry, 0.f), (float)(FH - 1));
    int wi = (int)fminf(fmaxf(rx, 0.f), (float)(FW - 1));
    float s0 = fold[844 + i*2 + 0];
    float s1 = fold[844 + i*2 + 1];
    int iy0 = hi*4 - 3, ix0 = wi*4 - 3;
    for (int kh = 0; kh < 7; ++kh) {
      int iy = iy0 + kh;
      if (iy < 0 || iy >= HH) continue;
      for (int kw = 0; kw < 7; ++kw) {
        int ix = ix0 + kw;
        if (ix < 0 || ix >= WW) continue;
        float xv = im[iy*WW + ix] - 0.5f;
        int t = kh*7 + kw;
        s0 = fmaf(fold[550 + (i*2 + 0)*KT + t], xv, s0);
        s1 = fmaf(fold[550 + (i*2 + 1)*KT + t], xv, s1);
      }
    }
    cx += s0;
    cy += s1;
  }
  out[p*2 + 0] = cx;
  out[p*2 + 1] = cy;
}

// ---------------------------------------------------------------------------
extern "C" void kernel_launch(void* const* d_in, const int* in_sizes, int n_in,
                              void* d_out, int out_size, void* d_ws, size_t ws_size,
                              hipStream_t stream) {
  const float* img = (const float*)d_in[0];   // (8,1,512,512)
  const float* bw  = (const float*)d_in[1];   // (256,3,7,7)
  const float* bb  = (const float*)d_in[2];   // (256,)
  const float* fcw = (const float*)d_in[3];   // (11,256)
  const float* fcb = (const float*)d_in[4];   // (11,)
  const float* hw  = (const float*)d_in[5];   // (3,256,2)
  const float* hb  = (const float*)d_in[6];   // (3,2)
  float* out = (float*)d_out;                 // (8,11,2) f32

  float* ws     = (float*)d_ws;
  float* fold   = ws + FOLD_OFF;
  float* scores = ws + SCORES_OFF;
  float* pval   = ws + PVAL_OFF;
  int*   pidx   = (int*)(ws + PIDX_OFF);

  fold_kernel<<<213, 256, 0, stream>>>(bw, bb, fcw, fcb, hw, hb, fold);
  scores_kernel<<<512, 256, 0, stream>>>(img, fold, scores);
  argmax_kernel<<<NBK*NSPLIT, 256, 0, stream>>>(scores, pval, pidx);
  cascade_kernel<<<1, 128, 0, stream>>>(img, fold, pval, pidx, out);
}